// Round 8
// baseline (827.080 us; speedup 1.0000x reference)
//
#include <hip/hip_runtime.h>

#define BB 512
#define TT 1024
#define DX 32
#define DZ 64
#define DY 256
#define ALPHA 0.125f
#define HP 36  // hid chunk stride: 32 floats + 4 pad (8 distinct bank-quads)

typedef float v2f __attribute__((ext_vector_type(2)));

// Packed dual-FP32 FMA (full-rate on gfx950; plain v_fma_f32 is half-rate).
__device__ __forceinline__ v2f pk_fma(v2f a, v2f b, v2f c) {
    asm("v_pk_fma_f32 %0, %1, %2, %0" : "+v"(c) : "v"(a), "v"(b));
    return c;
}

// DPP add: x + dpp_permuted(x). 0xB1 xor1 | 0x4E xor2 | 0x141 row_half_mirror.
template<int CTRL>
__device__ __forceinline__ float dpp_add(float x) {
    int p = __builtin_amdgcn_update_dpp(0, __float_as_int(x), CTRL, 0xF, 0xF, true);
    return x + __int_as_float(p);
}

// R6 structure (best: 799 us) + R7 change: X prefetch deepened to 4 steps.
// R0-R6 established: not LDS-BW-bound (R4), not issue-bound (R6: VALU halved,
// wall flat), chain-latency-bound. FETCH=33MB vs X=64MB -> ~half of X reads
// miss to HBM (~900 cy, m126); with only one step of slack the x-load sits ON
// the recurrence chain (blend -> zf_s -> barrier -> next m1). A 4-deep rolling
// register queue gives ~4 steps (~7500 cy) of slack.
// m1: thread (y=tid>>1, h=tid&1): hidden row y over z-chunk 32h..+31; xor1 DPP.
// m2: thread (z=tid>>3, oct=tid&7): latent row z over y-chunk 32*oct..+31;
//     xor1+xor2+half_mirror; update replicated across oct lanes, oct==0 stores.
__global__ __launch_bounds__(512, 4)
void plrnn_scan(const float* __restrict__ X, const float* __restrict__ A,
                const float* __restrict__ W1, const float* __restrict__ W2,
                const float* __restrict__ h1, const float* __restrict__ h2,
                float* __restrict__ out) {
    const int b   = blockIdx.x;
    const int tid = threadIdx.x;

    const int y   = tid >> 1;      // m1 output row 0..255
    const int h   = tid & 1;       // m1 z-chunk
    const int z   = tid >> 3;      // m2 output row 0..63
    const int oct = tid & 7;       // m2 y-chunk
    const int wv  = tid >> 6;      // wave id 0..7

    __shared__ float zf_s[DZ];
    __shared__ float hid_s[8 * HP];

    // ---- one-time: weight tiles into v2f pairs (32 + 32 floats) ----
    v2f w2p[16];   // pairs of W2[y][32h + ...]
    v2f w1p[16];   // pairs of W1[z][32*oct + ...]
#pragma unroll
    for (int j = 0; j < 8; ++j) {
        float4 t2 = *(const float4*)&W2[y * DZ + 32 * h + 4 * j];
        float4 t1 = *(const float4*)&W1[z * DY + 32 * oct + 4 * j];
        w2p[2 * j]     = v2f{t2.x, t2.y};
        w2p[2 * j + 1] = v2f{t2.z, t2.w};
        w1p[2 * j]     = v2f{t1.x, t1.y};
        w1p[2 * j + 1] = v2f{t1.z, t1.w};
    }
    const float h2i = (h == 0) ? h2[y] : 0.0f;    // bias folded into acc init
    const float h1i = (oct == 0) ? h1[z] : 0.0f;
    const float Ar  = A[z];
    const bool  zdx = (z < DX);    // wave-uniform (waves 0-3)

    const float* Xb = X   + (size_t)b * TT * DX;
    const float* xp = Xb + z;                     // X[t][z] group base
    float*       op = out + (size_t)b * TT * DX + z;
    const float NANF = __int_as_float(0x7fc00000);

    // ---- zf_0 = x0 (non-NaN) on first DX dims, else 0 (oct-replicated) ----
    float zfreg = 0.0f;
    if (zdx) { float x0 = xp[0]; zfreg = (x0 == x0) ? x0 : 0.0f; }
    if (oct == 0) zf_s[z] = zfreg;
    __syncthreads();

    const int hidx = wv * HP + (y & 31);   // m1 write slot (h==0 lanes)

    // one recurrence step; xn = forcing value X[t+1][z] (NaN -> blend skipped)
    auto step = [&](const float xn, const int koff) {
        // ---- m1: hidden = relu(W2 @ zf + h2) ----
        float4 zl4[8];
        {
            const float4* zp = (const float4*)(zf_s + 32 * h);
#pragma unroll
            for (int j = 0; j < 8; ++j) zl4[j] = zp[j];
        }
        v2f accA = {h2i, 0.f}, accB = {0.f, 0.f};
#pragma unroll
        for (int j = 0; j < 8; ++j) {
            accA = pk_fma(w2p[2 * j],     v2f{zl4[j].x, zl4[j].y}, accA);
            accB = pk_fma(w2p[2 * j + 1], v2f{zl4[j].z, zl4[j].w}, accB);
        }
        float d1 = (accA[0] + accB[0]) + (accA[1] + accB[1]);
        d1 = dpp_add<0xB1>(d1);                     // join the two z-halves
        if (h == 0) hid_s[hidx] = fmaxf(d1, 0.0f);
        __syncthreads();

        // ---- m2 + fused update: z_new = A*zf + W1 @ hidden + h1 ----
        float4 hl4[8];
        {
            const float4* hp = (const float4*)(hid_s + HP * oct);
#pragma unroll
            for (int j = 0; j < 8; ++j) hl4[j] = hp[j];
        }
        v2f acA = {h1i, 0.f}, acB = {0.f, 0.f};
#pragma unroll
        for (int j = 0; j < 8; ++j) {
            acA = pk_fma(w1p[2 * j],     v2f{hl4[j].x, hl4[j].y}, acA);
            acB = pk_fma(w1p[2 * j + 1], v2f{hl4[j].z, hl4[j].w}, acB);
        }
        float d2 = (acA[0] + acB[0]) + (acA[1] + acB[1]);
        d2 = dpp_add<0xB1>(d2);
        d2 = dpp_add<0x4E>(d2);
        d2 = dpp_add<0x141>(d2);                    // full 8-oct sum, all lanes

        float zn = fmaf(Ar, zfreg, d2);
        if (zdx) {                                  // wave-uniform branch
            if (oct == 0) op[koff * DX] = zn;
            zfreg = (xn == xn) ? fmaf(ALPHA, xn, 0.875f * zn) : zn;
        } else {
            zfreg = zn;
        }
        if (oct == 0) zf_s[z] = zfreg;
        __syncthreads();
    };

    // ---- prefetch queue: q0..q3 = X[tg+1..tg+4][z] ----
    float q0 = NANF, q1 = NANF, q2 = NANF, q3 = NANF;
    if (zdx) { q0 = xp[1 * DX]; q1 = xp[2 * DX]; q2 = xp[3 * DX]; q3 = xp[4 * DX]; }

    // main loop: groups of 4; reloads X[tg+5..tg+8] stay in bounds (tg<=TT-12)
    for (int tg = 0; tg < TT - 8; tg += 4) {
        float n0 = NANF, n1 = NANF, n2 = NANF, n3 = NANF;
        if (zdx) {   // issue 4-steps-ahead loads first: ~4 steps of slack
            n0 = xp[5 * DX]; n1 = xp[6 * DX]; n2 = xp[7 * DX]; n3 = xp[8 * DX];
        }
        step(q0, 0); step(q1, 1); step(q2, 2); step(q3, 3);
        q0 = n0; q1 = n1; q2 = n2; q3 = n3;
        xp += 4 * DX;
        op += 4 * DX;
    }
    // epilogue A: tg = TT-8, queue holds X[TT-7..TT-4]; shallow-load the rest
    float e0 = NANF, e1 = NANF, e2 = NANF;
    if (zdx) { e0 = xp[5 * DX]; e1 = xp[6 * DX]; e2 = xp[7 * DX]; } // X[TT-3..TT-1]
    step(q0, 0); step(q1, 1); step(q2, 2); step(q3, 3);
    op += 4 * DX;
    // epilogue B: t = TT-4..TT-1; last step has no next forcing -> NaN
    step(e0, 0); step(e1, 1); step(e2, 2); step(NANF, 3);
}

extern "C" void kernel_launch(void* const* d_in, const int* in_sizes, int n_in,
                              void* d_out, int out_size, void* d_ws, size_t ws_size,
                              hipStream_t stream) {
    const float* X  = (const float*)d_in[0];
    const float* A  = (const float*)d_in[1];
    const float* W1 = (const float*)d_in[2];
    const float* W2 = (const float*)d_in[3];
    const float* h1 = (const float*)d_in[4];
    const float* h2 = (const float*)d_in[5];
    float* out = (float*)d_out;

    plrnn_scan<<<BB, 512, 0, stream>>>(X, A, W1, W2, h1, h2, out);
}

// Round 9
// 825.693 us; speedup vs baseline: 1.0017x; 1.0017x over previous
//
#include <hip/hip_runtime.h>

#define BB 512
#define TT 1024
#define DX 32
#define DZ 64
#define DY 256
#define ALPHA 0.125f
#define HP 36  // hid chunk stride: 32 floats + 4 pad (8 distinct bank-quads)

typedef float v2f __attribute__((ext_vector_type(2)));

// Packed dual-FP32 FMA (full-rate on gfx950; plain v_fma_f32 is half-rate).
__device__ __forceinline__ v2f pk_fma(v2f a, v2f b, v2f c) {
    asm("v_pk_fma_f32 %0, %1, %2, %0" : "+v"(c) : "v"(a), "v"(b));
    return c;
}

// DPP add: x + dpp_permuted(x). 0xB1 xor1 | 0x4E xor2 | 0x141 row_half_mirror.
template<int CTRL>
__device__ __forceinline__ float dpp_add(float x) {
    int p = __builtin_amdgcn_update_dpp(0, __float_as_int(x), CTRL, 0xF, 0xF, true);
    return x + __int_as_float(p);
}

// Barrier that orders LDS ONLY (s_waitcnt lgkmcnt(0) + s_barrier), without
// __syncthreads' vmcnt(0) drain. Legal here: the only VMEM ops in the loop
// are the X prefetch loads (read-only) and the out stores (each address
// written by exactly one thread, never read) -- no cross-thread VMEM hazard.
// This takes the ~200-900cy global-memory round-trips OFF the per-step chain
// (they currently serialize at EVERY barrier; R7's load batching failed
// because the stores still drained). sched_barrier fences hoisting (rule 18).
__device__ __forceinline__ void lds_barrier() {
    __builtin_amdgcn_sched_barrier(0);
    asm volatile("s_waitcnt lgkmcnt(0)" ::: "memory");
    __builtin_amdgcn_s_barrier();
    __builtin_amdgcn_sched_barrier(0);
}

// R6/R7 structure (512 thr / 8 waves, 512 blocks -> 2 blocks/CU, pk_fma,
// 4-deep X prefetch) + lgkmcnt-only barriers in the hot loop.
// Elimination ledger: not LDS-BW (R4), not issue (R6), not load-depth (R7);
// remaining chain term = VMEM drain at __syncthreads (vmcnt(0)).
// m1: thread (y=tid>>1, h=tid&1): hidden row y over z-chunk 32h..+31; xor1 DPP.
// m2: thread (z=tid>>3, oct=tid&7): latent row z over y-chunk 32*oct..+31;
//     xor1+xor2+half_mirror; update replicated across oct lanes, oct==0 stores.
__global__ __launch_bounds__(512, 4)
void plrnn_scan(const float* __restrict__ X, const float* __restrict__ A,
                const float* __restrict__ W1, const float* __restrict__ W2,
                const float* __restrict__ h1, const float* __restrict__ h2,
                float* __restrict__ out) {
    const int b   = blockIdx.x;
    const int tid = threadIdx.x;

    const int y   = tid >> 1;      // m1 output row 0..255
    const int h   = tid & 1;       // m1 z-chunk
    const int z   = tid >> 3;      // m2 output row 0..63
    const int oct = tid & 7;       // m2 y-chunk
    const int wv  = tid >> 6;      // wave id 0..7

    __shared__ float zf_s[DZ];
    __shared__ float hid_s[8 * HP];

    // ---- one-time: weight tiles into v2f pairs (32 + 32 floats) ----
    v2f w2p[16];   // pairs of W2[y][32h + ...]
    v2f w1p[16];   // pairs of W1[z][32*oct + ...]
#pragma unroll
    for (int j = 0; j < 8; ++j) {
        float4 t2 = *(const float4*)&W2[y * DZ + 32 * h + 4 * j];
        float4 t1 = *(const float4*)&W1[z * DY + 32 * oct + 4 * j];
        w2p[2 * j]     = v2f{t2.x, t2.y};
        w2p[2 * j + 1] = v2f{t2.z, t2.w};
        w1p[2 * j]     = v2f{t1.x, t1.y};
        w1p[2 * j + 1] = v2f{t1.z, t1.w};
    }
    const float h2i = (h == 0) ? h2[y] : 0.0f;    // bias folded into acc init
    const float h1i = (oct == 0) ? h1[z] : 0.0f;
    const float Ar  = A[z];
    const bool  zdx = (z < DX);    // wave-uniform (waves 0-3)

    const float* Xb = X   + (size_t)b * TT * DX;
    const float* xp = Xb + z;                     // X[t][z] group base
    float*       op = out + (size_t)b * TT * DX + z;
    const float NANF = __int_as_float(0x7fc00000);

    // ---- zf_0 = x0 (non-NaN) on first DX dims, else 0 (oct-replicated) ----
    float zfreg = 0.0f;
    if (zdx) { float x0 = xp[0]; zfreg = (x0 == x0) ? x0 : 0.0f; }
    if (oct == 0) zf_s[z] = zfreg;
    __syncthreads();   // cold-start barrier: full drain is fine here

    const int hidx = wv * HP + (y & 31);   // m1 write slot (h==0 lanes)

    // one recurrence step; xn = forcing value X[t+1][z] (NaN -> blend skipped)
    auto step = [&](const float xn, const int koff) {
        // ---- m1: hidden = relu(W2 @ zf + h2) ----
        float4 zl4[8];
        {
            const float4* zp = (const float4*)(zf_s + 32 * h);
#pragma unroll
            for (int j = 0; j < 8; ++j) zl4[j] = zp[j];
        }
        v2f accA = {h2i, 0.f}, accB = {0.f, 0.f};
#pragma unroll
        for (int j = 0; j < 8; ++j) {
            accA = pk_fma(w2p[2 * j],     v2f{zl4[j].x, zl4[j].y}, accA);
            accB = pk_fma(w2p[2 * j + 1], v2f{zl4[j].z, zl4[j].w}, accB);
        }
        float d1 = (accA[0] + accB[0]) + (accA[1] + accB[1]);
        d1 = dpp_add<0xB1>(d1);                     // join the two z-halves
        if (h == 0) hid_s[hidx] = fmaxf(d1, 0.0f);
        lds_barrier();

        // ---- m2 + fused update: z_new = A*zf + W1 @ hidden + h1 ----
        float4 hl4[8];
        {
            const float4* hp = (const float4*)(hid_s + HP * oct);
#pragma unroll
            for (int j = 0; j < 8; ++j) hl4[j] = hp[j];
        }
        v2f acA = {h1i, 0.f}, acB = {0.f, 0.f};
#pragma unroll
        for (int j = 0; j < 8; ++j) {
            acA = pk_fma(w1p[2 * j],     v2f{hl4[j].x, hl4[j].y}, acA);
            acB = pk_fma(w1p[2 * j + 1], v2f{hl4[j].z, hl4[j].w}, acB);
        }
        float d2 = (acA[0] + acB[0]) + (acA[1] + acB[1]);
        d2 = dpp_add<0xB1>(d2);
        d2 = dpp_add<0x4E>(d2);
        d2 = dpp_add<0x141>(d2);                    // full 8-oct sum, all lanes

        float zn = fmaf(Ar, zfreg, d2);
        if (zdx) {                                  // wave-uniform branch
            if (oct == 0) op[koff * DX] = zn;
            zfreg = (xn == xn) ? fmaf(ALPHA, xn, 0.875f * zn) : zn;
        } else {
            zfreg = zn;
        }
        if (oct == 0) zf_s[z] = zfreg;
        lds_barrier();
    };

    // ---- prefetch queue: q0..q3 = X[tg+1..tg+4][z] ----
    float q0 = NANF, q1 = NANF, q2 = NANF, q3 = NANF;
    if (zdx) { q0 = xp[1 * DX]; q1 = xp[2 * DX]; q2 = xp[3 * DX]; q3 = xp[4 * DX]; }

    // main loop: groups of 4; reloads X[tg+5..tg+8] stay in bounds (tg<=TT-12)
    for (int tg = 0; tg < TT - 8; tg += 4) {
        float n0 = NANF, n1 = NANF, n2 = NANF, n3 = NANF;
        if (zdx) {   // issue 4-steps-ahead loads; no barrier drains them now
            n0 = xp[5 * DX]; n1 = xp[6 * DX]; n2 = xp[7 * DX]; n3 = xp[8 * DX];
        }
        step(q0, 0); step(q1, 1); step(q2, 2); step(q3, 3);
        q0 = n0; q1 = n1; q2 = n2; q3 = n3;
        xp += 4 * DX;
        op += 4 * DX;
    }
    // epilogue A: tg = TT-8, queue holds X[TT-7..TT-4]; shallow-load the rest
    float e0 = NANF, e1 = NANF, e2 = NANF;
    if (zdx) { e0 = xp[5 * DX]; e1 = xp[6 * DX]; e2 = xp[7 * DX]; } // X[TT-3..TT-1]
    step(q0, 0); step(q1, 1); step(q2, 2); step(q3, 3);
    op += 4 * DX;
    // epilogue B: t = TT-4..TT-1; last step has no next forcing -> NaN
    step(e0, 0); step(e1, 1); step(e2, 2); step(NANF, 3);
}

extern "C" void kernel_launch(void* const* d_in, const int* in_sizes, int n_in,
                              void* d_out, int out_size, void* d_ws, size_t ws_size,
                              hipStream_t stream) {
    const float* X  = (const float*)d_in[0];
    const float* A  = (const float*)d_in[1];
    const float* W1 = (const float*)d_in[2];
    const float* W2 = (const float*)d_in[3];
    const float* h1 = (const float*)d_in[4];
    const float* h2 = (const float*)d_in[5];
    float* out = (float*)d_out;

    plrnn_scan<<<BB, 512, 0, stream>>>(X, A, W1, W2, h1, h2, out);
}

// Round 10
// 822.730 us; speedup vs baseline: 1.0053x; 1.0036x over previous
//
#include <hip/hip_runtime.h>

#define BB 512
#define TT 1024
#define DX 32
#define DZ 64
#define DY 256
#define ALPHA 0.125f
#define HP 36  // hid chunk stride: 32 floats + 4 pad (8 distinct bank-quads)

typedef float v2f __attribute__((ext_vector_type(2)));

// Packed dual-FP32 FMA (full-rate on gfx950; plain v_fma_f32 is half-rate).
__device__ __forceinline__ v2f pk_fma(v2f a, v2f b, v2f c) {
    asm("v_pk_fma_f32 %0, %1, %2, %0" : "+v"(c) : "v"(a), "v"(b));
    return c;
}

// DPP add: x + dpp_permuted(x). 0xB1 xor1 | 0x4E xor2 | 0x141 row_half_mirror.
template<int CTRL>
__device__ __forceinline__ float dpp_add(float x) {
    int p = __builtin_amdgcn_update_dpp(0, __float_as_int(x), CTRL, 0xF, 0xF, true);
    return x + __int_as_float(p);
}

// LDS-only barrier (no vmcnt drain; proven safe/neutral in R9).
__device__ __forceinline__ void lds_barrier() {
    __builtin_amdgcn_sched_barrier(0);
    asm volatile("s_waitcnt lgkmcnt(0)" ::: "memory");
    __builtin_amdgcn_s_barrier();
    __builtin_amdgcn_sched_barrier(0);
}

// R10 = R6 (best, 799us) + TRUE weight residency.
// Diagnosis: R6's VGPR_Count=64 proves the 64 weight floats/thread were
// re-loaded from L1/L2 EVERY step (compiler sank the loads into the loop).
// That is 128KB/block/step of L2 traffic: ~2200 B/cy demand per XCD vs
// ~1800 B/cy L2 supply, plus ~200cy L2 latency on the chain -- the invisible
// wall behind R1/R4/R6/R9's flatness (FETCH_SIZE only counts HBM).
// Fix: pin the weight registers INSIDE the loop -- each iteration's FMAs
// consume the previous iteration's asm output, which cannot be
// rematerialized from memory, so the values must stay in VGPRs across the
// backedge. waves_per_eu(4,4) sets the allocator budget to 128 (grid gives
// exactly 2 blocks/CU x 8 waves = 4 waves/SIMD).
// m1: thread (y=tid>>1, h=tid&1): hidden row y over z-chunk 32h..+31; xor1 DPP.
// m2: thread (z=tid>>3, oct=tid&7): latent row z over y-chunk 32*oct..+31;
//     xor1+xor2+half_mirror; update replicated across oct lanes, oct==0 stores.
__global__ __launch_bounds__(512)
__attribute__((amdgpu_waves_per_eu(4, 4)))
void plrnn_scan(const float* __restrict__ X, const float* __restrict__ A,
                const float* __restrict__ W1, const float* __restrict__ W2,
                const float* __restrict__ h1, const float* __restrict__ h2,
                float* __restrict__ out) {
    const int b   = blockIdx.x;
    const int tid = threadIdx.x;

    const int y   = tid >> 1;      // m1 output row 0..255
    const int h   = tid & 1;       // m1 z-chunk
    const int z   = tid >> 3;      // m2 output row 0..63
    const int oct = tid & 7;       // m2 y-chunk
    const int wv  = tid >> 6;      // wave id 0..7

    __shared__ float zf_s[DZ];
    __shared__ float hid_s[8 * HP];

    // ---- one-time: weight tiles into v2f pairs (32 + 32 floats) ----
    v2f w2p[16];   // pairs of W2[y][32h + ...]
    v2f w1p[16];   // pairs of W1[z][32*oct + ...]
#pragma unroll
    for (int j = 0; j < 8; ++j) {
        float4 t2 = *(const float4*)&W2[y * DZ + 32 * h + 4 * j];
        float4 t1 = *(const float4*)&W1[z * DY + 32 * oct + 4 * j];
        w2p[2 * j]     = v2f{t2.x, t2.y};
        w2p[2 * j + 1] = v2f{t2.z, t2.w};
        w1p[2 * j]     = v2f{t1.x, t1.y};
        w1p[2 * j + 1] = v2f{t1.z, t1.w};
    }
    const float h2i = (h == 0) ? h2[y] : 0.0f;    // bias folded into acc init
    const float h1i = (oct == 0) ? h1[z] : 0.0f;
    const float Ar  = A[z];
    const bool  zdx = (z < DX);    // wave-uniform (waves 0-3)

    const float* Xb = X   + (size_t)b * TT * DX;
    float*       op = out + (size_t)b * TT * DX + z;
    const float* xq = Xb + DX + z;                 // X[t+1][z] stream
    const float NANF = __int_as_float(0x7fc00000);

    // ---- zf_0 = x0 (non-NaN) on first DX dims, else 0 (oct-replicated) ----
    float zfreg = 0.0f;
    if (zdx) { float x0 = Xb[z]; zfreg = (x0 == x0) ? x0 : 0.0f; }
    if (oct == 0) zf_s[z] = zfreg;
    __syncthreads();

    const int hidx = wv * HP + (y & 31);   // m1 write slot (h==0 lanes)

    for (int t = 0; t < TT; ++t) {
        // ---- residency pins: each iteration "redefines" the weight regs, so
        // the FMAs below consume asm outputs that cannot be rematerialized
        // from memory -> weights stay in VGPRs across the backedge. ----
#pragma unroll
        for (int j = 0; j < 16; ++j) {
            asm volatile("" : "+v"(w2p[j]));
            asm volatile("" : "+v"(w1p[j]));
        }

        // prefetch next forcing value (consumed at the m2 tail)
        float xnext = NANF;
        if (zdx && (t + 1) < TT) xnext = xq[0];
        xq += DX;

        // ---- m1: hidden = relu(W2 @ zf + h2) ----
        float4 zl4[8];
        {
            const float4* zp = (const float4*)(zf_s + 32 * h);
#pragma unroll
            for (int j = 0; j < 8; ++j) zl4[j] = zp[j];
        }
        v2f accA = {h2i, 0.f}, accB = {0.f, 0.f};
#pragma unroll
        for (int j = 0; j < 8; ++j) {
            accA = pk_fma(w2p[2 * j],     v2f{zl4[j].x, zl4[j].y}, accA);
            accB = pk_fma(w2p[2 * j + 1], v2f{zl4[j].z, zl4[j].w}, accB);
        }
        float d1 = (accA[0] + accB[0]) + (accA[1] + accB[1]);
        d1 = dpp_add<0xB1>(d1);                     // join the two z-halves
        if (h == 0) hid_s[hidx] = fmaxf(d1, 0.0f);
        lds_barrier();

        // ---- m2 + fused update: z_new = A*zf + W1 @ hidden + h1 ----
        float4 hl4[8];
        {
            const float4* hp = (const float4*)(hid_s + HP * oct);
#pragma unroll
            for (int j = 0; j < 8; ++j) hl4[j] = hp[j];
        }
        v2f acA = {h1i, 0.f}, acB = {0.f, 0.f};
#pragma unroll
        for (int j = 0; j < 8; ++j) {
            acA = pk_fma(w1p[2 * j],     v2f{hl4[j].x, hl4[j].y}, acA);
            acB = pk_fma(w1p[2 * j + 1], v2f{hl4[j].z, hl4[j].w}, acB);
        }
        float d2 = (acA[0] + acB[0]) + (acA[1] + acB[1]);
        d2 = dpp_add<0xB1>(d2);
        d2 = dpp_add<0x4E>(d2);
        d2 = dpp_add<0x141>(d2);                    // full 8-oct sum, all lanes

        float zn = fmaf(Ar, zfreg, d2);
        if (zdx) {                                  // wave-uniform branch
            if (oct == 0) *op = zn;
            zfreg = (xnext == xnext) ? fmaf(ALPHA, xnext, 0.875f * zn) : zn;
        } else {
            zfreg = zn;
        }
        if (oct == 0) zf_s[z] = zfreg;
        op += DX;
        lds_barrier();
    }
}

extern "C" void kernel_launch(void* const* d_in, const int* in_sizes, int n_in,
                              void* d_out, int out_size, void* d_ws, size_t ws_size,
                              hipStream_t stream) {
    const float* X  = (const float*)d_in[0];
    const float* A  = (const float*)d_in[1];
    const float* W1 = (const float*)d_in[2];
    const float* W2 = (const float*)d_in[3];
    const float* h1 = (const float*)d_in[4];
    const float* h2 = (const float*)d_in[5];
    float* out = (float*)d_out;

    plrnn_scan<<<BB, 512, 0, stream>>>(X, A, W1, W2, h1, h2, out);
}